// Round 5
// baseline (280.410 us; speedup 1.0000x reference)
//
#include <hip/hip_runtime.h>
#include <math.h>

// ---------------------------------------------------------------------------
// GCN fraud-model forward:
//   out = A(relu(A(x*sig(mask) @ W1) + b1) @ (W2@Wc)) + (b2@Wc + bc)
// A-linearity folds W2@Wc -> [128,2].
//
// R1: CSR build XCD-range-partitioned (fill WRITE_SIZE 105MB -> ~7MB).
// R3: dinv folded into stored rows; H1n stored packed bf16 (256B/row).
// R4: gemm1 -> MFMA bf16 32x32x16, XOR-swizzled LDS (101us -> <20us).
// R5: CSR build redundancy fix. count/fill each re-scanned the edge list 8x
//     (once per XCD range) = ~140us combined. Now: single-pass 8-bin radix
//     partition of edges by dst range (hist -> scan -> scatter), then
//     count_part/fill_part read only their partition once; atomics stay
//     XCD-local (blockIdx&7 = range = XCD). dinv fused into scanA. agg1
//     gather unrolled 8-deep for MLP.
// ---------------------------------------------------------------------------

constexpr int NRANGE = 8;  // = XCD count on MI355X
constexpr int PNB = 512;   // partition blocks (hist/scatter)

typedef __attribute__((ext_vector_type(8))) short bf16x8;
typedef __attribute__((ext_vector_type(16))) float f32x16;

__device__ __forceinline__ unsigned bf16rtn(float f) {
  unsigned b = __float_as_uint(f);
  b += 0x7FFFu + ((b >> 16) & 1u);   // round-to-nearest-even
  return b >> 16;
}
__device__ __forceinline__ float2 bf2unpack(unsigned u) {
  float2 r;
  r.x = __uint_as_float(u << 16);
  r.y = __uint_as_float(u & 0xFFFF0000u);
  return r;
}

// ---------- tiny prep: sigmoid(mask), Wf = W2@Wc [128,2], bf = b2@Wc + bc ----
__global__ void prep_kernel(const float* __restrict__ fmask, const float* __restrict__ W2,
                            const float* __restrict__ b2, const float* __restrict__ Wc,
                            const float* __restrict__ bc, float* __restrict__ sm,
                            float* __restrict__ Wf, float* __restrict__ bf) {
  int t = threadIdx.x;
  if (t < 128) {
    sm[t] = 1.0f / (1.0f + expf(-fmask[t]));
    float w0 = 0.f, w1 = 0.f;
    for (int k = 0; k < 128; ++k) {
      float v = W2[t * 128 + k];
      w0 = fmaf(v, Wc[k * 2 + 0], w0);
      w1 = fmaf(v, Wc[k * 2 + 1], w1);
    }
    Wf[t * 2 + 0] = w0;
    Wf[t * 2 + 1] = w1;
  }
  if (t < 2) {
    float s = bc[t];
    for (int k = 0; k < 128; ++k) s = fmaf(b2[k], Wc[k * 2 + t], s);
    bf[t] = s;
  }
}

// ---------- W1 -> bf16 transposed: W1Tg u32[j*64 + k/2] = {W1[k][j],W1[k+1][j]} ----
__global__ void w1t_kernel(const float* __restrict__ W1, unsigned* __restrict__ W1Tg) {
  int p = blockIdx.x * blockDim.x + threadIdx.x;  // 0..8191
  if (p >= 8192) return;
  int j = p >> 6;
  int kp = (p & 63) * 2;
  float a = W1[(size_t)kp * 128 + j];
  float b = W1[(size_t)(kp + 1) * 128 + j];
  W1Tg[p] = bf16rtn(a) | (bf16rtn(b) << 16);
}

// ---------- partition pass 1: per-(bin,block) histogram ----------
__global__ void histP_kernel(const int* __restrict__ dst, int* __restrict__ hist,
                             int E, unsigned mult) {
  __shared__ int h[NRANGE];
  int t = threadIdx.x;
  if (t < NRANGE) h[t] = 0;
  __syncthreads();
  int per = (E + PNB - 1) / PNB;
  int e0 = blockIdx.x * per, e1 = min(E, e0 + per);
  for (int e = e0 + t; e < e1; e += blockDim.x) {
    unsigned d = (unsigned)dst[e];
    int b = __umulhi(d, mult);
    atomicAdd(&h[b], 1);
  }
  __syncthreads();
  if (t < NRANGE) hist[t * PNB + blockIdx.x] = h[t];
}

// ---------- partition pass 2: exclusive scan of hist[8*PNB], emit binstart ----
__global__ void scanP_kernel(int* __restrict__ hist, int* __restrict__ binstart, int E) {
  __shared__ int sh[256];
  int t = threadIdx.x;
  int v[16];
  int s = 0;
#pragma unroll
  for (int j = 0; j < 16; ++j) {
    v[j] = hist[t * 16 + j];
    s += v[j];
  }
  sh[t] = s;
  __syncthreads();
  for (int off = 1; off < 256; off <<= 1) {
    int add = (t >= off) ? sh[t - off] : 0;
    __syncthreads();
    sh[t] += add;
    __syncthreads();
  }
  int run = sh[t] - s;  // exclusive
#pragma unroll
  for (int j = 0; j < 16; ++j) {
    int idx = t * 16 + j;
    hist[idx] = run;
    if ((idx & (PNB - 1)) == 0) binstart[idx / PNB] = run;
    run += v[j];
  }
  if (t == 0) binstart[NRANGE] = E;
}

// ---------- partition pass 3: scatter (src,dst) into dst-range bins ----------
__global__ void partP_kernel(const int* __restrict__ src, const int* __restrict__ dst,
                             const int* __restrict__ hist, int* __restrict__ psrc,
                             int* __restrict__ pdst, int E, unsigned mult) {
  __shared__ int cur[NRANGE];
  int t = threadIdx.x;
  if (t < NRANGE) cur[t] = hist[t * PNB + blockIdx.x];
  __syncthreads();
  int per = (E + PNB - 1) / PNB;
  int e0 = blockIdx.x * per, e1 = min(E, e0 + per);
  for (int e = e0 + t; e < e1; e += blockDim.x) {
    int d = dst[e];
    int s = src[e];
    int b = __umulhi((unsigned)d, mult);
    int p = atomicAdd(&cur[b], 1);
    pdst[p] = d;
    psrc[p] = s;
  }
}

// ---------- degree count: each XCD range reads only its partition ----------
__global__ void count_part_kernel(const int* __restrict__ pdst,
                                  const int* __restrict__ binstart,
                                  int* __restrict__ counts) {
  int r = blockIdx.x & (NRANGE - 1);
  int c = blockIdx.x >> 3;
  int nch = gridDim.x >> 3;
  int a = binstart[r], b = binstart[r + 1];
  int per = (b - a + nch - 1) / nch;
  int s0 = a + c * per, s1 = min(b, s0 + per);
  for (int e = s0 + (int)threadIdx.x; e < s1; e += blockDim.x)
    atomicAdd(&counts[pdst[e]], 1);
}

// ---------- 3-phase exclusive scan of counts; scanA also emits dinv ----------
__global__ void scanA_kernel(const int* __restrict__ counts, int* __restrict__ bsum,
                             float* __restrict__ dinv, int n) {
  __shared__ int sh[256];
  int t = threadIdx.x;
  int base = blockIdx.x * 1024 + t * 4;
  int s = 0;
#pragma unroll
  for (int j = 0; j < 4; ++j) {
    int idx = base + j;
    if (idx < n) {
      int c = counts[idx];
      s += c;
      dinv[idx] = rsqrtf((float)(c + 1));
    }
  }
  sh[t] = s;
  __syncthreads();
#pragma unroll
  for (int m = 128; m > 0; m >>= 1) {
    if (t < m) sh[t] += sh[t + m];
    __syncthreads();
  }
  if (t == 0) bsum[blockIdx.x] = sh[0];
}

__global__ void scanB_kernel(int* __restrict__ bsum, int nb) {
  __shared__ int sh[256];
  int t = threadIdx.x;
  int v = (t < nb) ? bsum[t] : 0;
  sh[t] = v;
  __syncthreads();
  for (int off = 1; off < 256; off <<= 1) {
    int add = (t >= off) ? sh[t - off] : 0;
    __syncthreads();
    sh[t] += add;
    __syncthreads();
  }
  if (t < nb) bsum[t] = sh[t] - v;  // exclusive
}

__global__ void scanC_kernel(const int* __restrict__ counts, const int* __restrict__ bsum,
                             int* __restrict__ offsets, int* __restrict__ cursor, int n) {
  __shared__ int sh[256];
  int t = threadIdx.x;
  int base = blockIdx.x * 1024 + t * 4;
  int c[4];
  int loc = 0;
#pragma unroll
  for (int j = 0; j < 4; ++j) {
    int idx = base + j;
    c[j] = (idx < n) ? counts[idx] : 0;
    loc += c[j];
  }
  sh[t] = loc;
  __syncthreads();
  for (int off = 1; off < 256; off <<= 1) {
    int add = (t >= off) ? sh[t - off] : 0;
    __syncthreads();
    sh[t] += add;
    __syncthreads();
  }
  int run = bsum[blockIdx.x] + sh[t] - loc;
#pragma unroll
  for (int j = 0; j < 4; ++j) {
    int idx = base + j;
    if (idx < n) {
      offsets[idx] = run;
      cursor[idx] = run;
    }
    run += c[j];
  }
}

// ---------- CSR fill: each XCD range reads only its partition ----------
__global__ void fill_part_kernel(const int* __restrict__ psrc, const int* __restrict__ pdst,
                                 const int* __restrict__ binstart, int* __restrict__ cursor,
                                 int* __restrict__ csr) {
  int r = blockIdx.x & (NRANGE - 1);
  int c = blockIdx.x >> 3;
  int nch = gridDim.x >> 3;
  int a = binstart[r], b = binstart[r + 1];
  int per = (b - a + nch - 1) / nch;
  int s0 = a + c * per, s1 = min(b, s0 + per);
  for (int e = s0 + (int)threadIdx.x; e < s1; e += blockDim.x) {
    int d = pdst[e];
    int p = atomicAdd(&cursor[d], 1);
    csr[p] = psrc[e];
  }
}

// ---------- GEMM1 (MFMA): H1n = dinv[row] * ((x*sm) @ W1) in packed bf16 ----
__global__ __launch_bounds__(256) void gemm1_mfma_kernel(
    const float* __restrict__ x, const unsigned* __restrict__ W1Tg,
    const float* __restrict__ sm, const float* __restrict__ dinv,
    unsigned* __restrict__ H1n, int n) {
  __shared__ short lw1t[16384];  // 32 KB, W1T[j][k] bf16, swizzled
  __shared__ short lA[16384];    // 32 KB, A[r][k] bf16, swizzled
  __shared__ float ldv[128];
  int t = threadIdx.x;
  int rowbase = blockIdx.x * 128;

  if (t < 128) {
    int rg = rowbase + t;
    ldv[t] = (rg < n) ? dinv[rg] : 0.f;
  }
#pragma unroll
  for (int i = 0; i < 8; ++i) {
    int g = t + i * 256;
    int j = g >> 4;
    int c8 = (g & 15) * 8;
    uint4 v = *(const uint4*)(W1Tg + j * 64 + (c8 >> 1));
    int so = (j * 128 + c8) ^ ((j & 7) << 3);
    *(uint4*)(&lw1t[so]) = v;
  }
#pragma unroll
  for (int i = 0; i < 8; ++i) {
    int g = t + i * 256;
    int r = g >> 4;
    int c8 = (g & 15) * 8;
    int rowg = rowbase + r;
    uint4 p = {0, 0, 0, 0};
    if (rowg < n) {
      const float* xp = x + (size_t)rowg * 128 + c8;
      float4 xa = *(const float4*)(xp);
      float4 xb = *(const float4*)(xp + 4);
      float4 sa = *(const float4*)(sm + c8);
      float4 sb = *(const float4*)(sm + c8 + 4);
      p.x = bf16rtn(xa.x * sa.x) | (bf16rtn(xa.y * sa.y) << 16);
      p.y = bf16rtn(xa.z * sa.z) | (bf16rtn(xa.w * sa.w) << 16);
      p.z = bf16rtn(xb.x * sb.x) | (bf16rtn(xb.y * sb.y) << 16);
      p.w = bf16rtn(xb.z * sb.z) | (bf16rtn(xb.w * sb.w) << 16);
    }
    int so = (r * 128 + c8) ^ ((r & 7) << 3);
    *(uint4*)(&lA[so]) = p;
  }
  __syncthreads();

  int l = t & 63;
  int w = t >> 6;
  int wbase = w * 32;
  int lp = l & 31;
  int lhi = l >> 5;

  bf16x8 af[8];
#pragma unroll
  for (int kb = 0; kb < 8; ++kb) {
    int row = wbase + lp;
    int so = (row * 128 + kb * 16 + lhi * 8) ^ ((row & 7) << 3);
    af[kb] = *(const bf16x8*)(&lA[so]);
  }
  f32x16 acc0 = {}, acc1 = {}, acc2 = {}, acc3 = {};
#pragma unroll
  for (int kb = 0; kb < 8; ++kb) {
    int ko = kb * 16 + lhi * 8;
    int sw = (lp & 7) << 3;
    bf16x8 b0 = *(const bf16x8*)(&lw1t[((lp + 0) * 128 + ko) ^ sw]);
    bf16x8 b1 = *(const bf16x8*)(&lw1t[((lp + 32) * 128 + ko) ^ sw]);
    bf16x8 b2 = *(const bf16x8*)(&lw1t[((lp + 64) * 128 + ko) ^ sw]);
    bf16x8 b3 = *(const bf16x8*)(&lw1t[((lp + 96) * 128 + ko) ^ sw]);
    acc0 = __builtin_amdgcn_mfma_f32_32x32x16_bf16(af[kb], b0, acc0, 0, 0, 0);
    acc1 = __builtin_amdgcn_mfma_f32_32x32x16_bf16(af[kb], b1, acc1, 0, 0, 0);
    acc2 = __builtin_amdgcn_mfma_f32_32x32x16_bf16(af[kb], b2, acc2, 0, 0, 0);
    acc3 = __builtin_amdgcn_mfma_f32_32x32x16_bf16(af[kb], b3, acc3, 0, 0, 0);
  }

#pragma unroll
  for (int r = 0; r < 16; ++r) {
    int row_local = wbase + (r & 3) + 8 * (r >> 2) + 4 * lhi;
    float dv = ldv[row_local];
    int rowg = rowbase + row_local;
    bool ok = (rowg < n) && !(l & 1);
    size_t base = (size_t)rowg * 64 + (lp >> 1);
    {
      float v = acc0[r] * dv; float o = __shfl_xor(v, 1, 64);
      if (ok) H1n[base + 0] = bf16rtn(v) | (bf16rtn(o) << 16);
    }
    {
      float v = acc1[r] * dv; float o = __shfl_xor(v, 1, 64);
      if (ok) H1n[base + 16] = bf16rtn(v) | (bf16rtn(o) << 16);
    }
    {
      float v = acc2[r] * dv; float o = __shfl_xor(v, 1, 64);
      if (ok) H1n[base + 32] = bf16rtn(v) | (bf16rtn(o) << 16);
    }
    {
      float v = acc3[r] * dv; float o = __shfl_xor(v, 1, 64);
      if (ok) H1n[base + 48] = bf16rtn(v) | (bf16rtn(o) << 16);
    }
  }
}

// ---------- agg1 (wave per node): sum bf16 rows, h1 = relu(di*acc+b1),
//            Zn = di * (h1 @ Wf) ----------
__global__ __launch_bounds__(256) void agg1_kernel(
    const unsigned* __restrict__ H1n, const int* __restrict__ csr,
    const int* __restrict__ offsets, const int* __restrict__ counts,
    const float* __restrict__ dinv, const float* __restrict__ b1,
    const float* __restrict__ Wf, float* __restrict__ Zn, int n) {
  int lane = threadIdx.x & 63;
  int node = blockIdx.x * 4 + (threadIdx.x >> 6);
  if (node >= n) return;
  int c0 = lane * 2;

  float di = dinv[node];
  float2 acc = bf2unpack(H1n[(size_t)node * 64 + lane]);  // self-loop term

  int off = offsets[node];
  int cnt = counts[node];
  int e = 0;
  for (; e + 8 <= cnt; e += 8) {
    int s[8];
#pragma unroll
    for (int j = 0; j < 8; ++j) s[j] = csr[off + e + j];
    unsigned u[8];
#pragma unroll
    for (int j = 0; j < 8; ++j) u[j] = H1n[(size_t)s[j] * 64 + lane];
#pragma unroll
    for (int j = 0; j < 8; ++j) {
      float2 h = bf2unpack(u[j]);
      acc.x += h.x;
      acc.y += h.y;
    }
  }
  for (; e + 2 <= cnt; e += 2) {
    int s0 = csr[off + e], s1 = csr[off + e + 1];
    unsigned u0 = H1n[(size_t)s0 * 64 + lane];
    unsigned u1 = H1n[(size_t)s1 * 64 + lane];
    float2 h0 = bf2unpack(u0), h1v = bf2unpack(u1);
    acc.x += h0.x + h1v.x;
    acc.y += h0.y + h1v.y;
  }
  if (e < cnt) {
    int s0 = csr[off + e];
    float2 h0 = bf2unpack(H1n[(size_t)s0 * 64 + lane]);
    acc.x += h0.x;
    acc.y += h0.y;
  }

  float2 bb = *(const float2*)(b1 + c0);
  float v0 = fmaf(acc.x, di, bb.x); v0 = v0 > 0.f ? v0 : 0.f;
  float v1 = fmaf(acc.y, di, bb.y); v1 = v1 > 0.f ? v1 : 0.f;

  float4 wv = *(const float4*)(Wf + c0 * 2);
  float z0 = v0 * wv.x + v1 * wv.z;
  float z1 = v0 * wv.y + v1 * wv.w;
#pragma unroll
  for (int m = 32; m > 0; m >>= 1) {
    z0 += __shfl_xor(z0, m, 64);
    z1 += __shfl_xor(z1, m, 64);
  }
  if (lane == 0) {
    Zn[(size_t)node * 2 + 0] = z0 * di;
    Zn[(size_t)node * 2 + 1] = z1 * di;
  }
}

// ---------- agg2 (thread per node): out = di*(Zn[i] + sum Zn[s]) + bf ----------
__global__ void agg2_kernel(const float* __restrict__ Znb, const int* __restrict__ csr,
                            const int* __restrict__ offsets, const int* __restrict__ counts,
                            const float* __restrict__ dinv, const float* __restrict__ bf,
                            float* __restrict__ out, int n) {
  int i = blockIdx.x * blockDim.x + threadIdx.x;
  if (i >= n) return;
  float di = dinv[i];
  float2 z = *(const float2*)(Znb + (size_t)i * 2);
  float ax = z.x, ay = z.y;   // self-loop term
  int off = offsets[i], cnt = counts[i];
  for (int e = 0; e < cnt; ++e) {
    int s = csr[off + e];
    float2 zs = *(const float2*)(Znb + (size_t)s * 2);
    ax += zs.x;
    ay += zs.y;
  }
  out[(size_t)i * 2 + 0] = fmaf(ax, di, bf[0]);
  out[(size_t)i * 2 + 1] = fmaf(ay, di, bf[1]);
}

extern "C" void kernel_launch(void* const* d_in, const int* in_sizes, int n_in,
                              void* d_out, int out_size, void* d_ws, size_t ws_size,
                              hipStream_t stream) {
  const float* x = (const float*)d_in[0];
  const int* ei = (const int*)d_in[1];
  const float* fmask = (const float*)d_in[2];
  const float* W1 = (const float*)d_in[3];
  const float* b1 = (const float*)d_in[4];
  const float* W2 = (const float*)d_in[5];
  const float* b2 = (const float*)d_in[6];
  const float* Wc = (const float*)d_in[7];
  const float* bc = (const float*)d_in[8];

  int N = in_sizes[0] / 128;
  int E = in_sizes[1] / 2;
  const int* src = ei;
  const int* dst = ei + E;

  char* base = (char*)d_ws;
  size_t o = 0;
  auto take = [&](size_t bytes) -> char* {
    char* p = base + o;
    o = (o + bytes + 255) & ~(size_t)255;
    return p;
  };
  int* counts = (int*)take((size_t)N * 4);
  int* offsets = (int*)take((size_t)N * 4);
  int* cursor = (int*)take((size_t)N * 4);
  int* bsum = (int*)take(256 * 4);
  float* dinv = (float*)take((size_t)N * 4);
  int* csr = (int*)take((size_t)E * 4);
  unsigned* H1n = (unsigned*)take((size_t)N * 64 * 4);  // packed bf16 rows
  float* Zn = (float*)take((size_t)N * 2 * 4);
  float* sm = (float*)take(128 * 4);
  float* Wf = (float*)take(256 * 4);
  float* bf = (float*)take(2 * 4);
  unsigned* W1Tg = (unsigned*)take(8192 * 4);           // W1^T bf16 packed
  int* hist = (int*)take((size_t)NRANGE * PNB * 4);     // partition histogram
  int* binstart = (int*)take((NRANGE + 1) * 4);
  int* psrc = (int*)take((size_t)E * 4);                // partitioned edges
  int* pdst = (int*)take((size_t)E * 4);
  (void)ws_size;
  (void)n_in;
  (void)out_size;

  // bin = umulhi(d, mult) in [0, 8)
  unsigned mult = (unsigned)((((unsigned long long)NRANGE << 32) + N - 1) / N);

  hipMemsetAsync(counts, 0, (size_t)N * 4, stream);
  prep_kernel<<<1, 128, 0, stream>>>(fmask, W2, b2, Wc, bc, sm, Wf, bf);
  w1t_kernel<<<32, 256, 0, stream>>>(W1, W1Tg);
  histP_kernel<<<PNB, 256, 0, stream>>>(dst, hist, E, mult);
  scanP_kernel<<<1, 256, 0, stream>>>(hist, binstart, E);
  partP_kernel<<<PNB, 256, 0, stream>>>(src, dst, hist, psrc, pdst, E, mult);
  count_part_kernel<<<NRANGE * 128, 256, 0, stream>>>(pdst, binstart, counts);
  int nb = (N + 1023) / 1024;
  scanA_kernel<<<nb, 256, 0, stream>>>(counts, bsum, dinv, N);
  scanB_kernel<<<1, 256, 0, stream>>>(bsum, nb);
  scanC_kernel<<<nb, 256, 0, stream>>>(counts, bsum, offsets, cursor, N);
  fill_part_kernel<<<NRANGE * 128, 256, 0, stream>>>(psrc, pdst, binstart, cursor, csr);
  gemm1_mfma_kernel<<<(N + 127) / 128, 256, 0, stream>>>(x, W1Tg, sm, dinv, H1n, N);
  agg1_kernel<<<(N + 3) / 4, 256, 0, stream>>>(H1n, csr, offsets, counts, dinv, b1, Wf, Zn, N);
  agg2_kernel<<<(N + 255) / 256, 256, 0, stream>>>(Zn, csr, offsets, counts, dinv, bf,
                                                   (float*)d_out, N);
}

// Round 6
// 191.015 us; speedup vs baseline: 1.4680x; 1.4680x over previous
//
#include <hip/hip_runtime.h>
#include <math.h>

// ---------------------------------------------------------------------------
// GCN fraud-model forward:
//   out = A(relu(A(x*sig(mask) @ W1) + b1) @ (W2@Wc)) + (b2@Wc + bc)
// A-linearity folds W2@Wc -> [128,2].
//
// R3: dinv folded into stored rows; H1n stored packed bf16 (256B/row).
// R4: gemm1 -> MFMA bf16 32x32x16, XOR-swizzled LDS (101us -> <20us).
// R6: CSR build rebuilt around line-level write locality. R5 profile: fill's
//     4B random scatter wrote 63MB for a 6.4MB array (lines evicted
//     part-filled). Now: 128-bin partition (bins = ~781-node ranges; each
//     (bin,block) slot range is RESERVED via scanned histogram -> contiguous
//     runs, no cross-block line sharing), then one block per bin builds its
//     CSR slice entirely locally: LDS degree count -> block scan -> coalesced
//     offsets/counts/dinv -> scatter csr inside a private ~50KB window.
//     Replaces count + scanA/B/C + dinv + fill (~150us) with ~40us.
// ---------------------------------------------------------------------------

constexpr int NBIN = 128;  // partition bins (~781 nodes, ~12.5K edges each)
constexpr int PNB = 256;   // histogram/scatter blocks

typedef __attribute__((ext_vector_type(8))) short bf16x8;
typedef __attribute__((ext_vector_type(16))) float f32x16;

__device__ __forceinline__ unsigned bf16rtn(float f) {
  unsigned b = __float_as_uint(f);
  b += 0x7FFFu + ((b >> 16) & 1u);   // round-to-nearest-even
  return b >> 16;
}
__device__ __forceinline__ float2 bf2unpack(unsigned u) {
  float2 r;
  r.x = __uint_as_float(u << 16);
  r.y = __uint_as_float(u & 0xFFFF0000u);
  return r;
}

// ---------- tiny prep: sigmoid(mask), Wf = W2@Wc [128,2], bf = b2@Wc + bc ----
__global__ void prep_kernel(const float* __restrict__ fmask, const float* __restrict__ W2,
                            const float* __restrict__ b2, const float* __restrict__ Wc,
                            const float* __restrict__ bc, float* __restrict__ sm,
                            float* __restrict__ Wf, float* __restrict__ bf) {
  int t = threadIdx.x;
  if (t < 128) {
    sm[t] = 1.0f / (1.0f + expf(-fmask[t]));
    float w0 = 0.f, w1 = 0.f;
    for (int k = 0; k < 128; ++k) {
      float v = W2[t * 128 + k];
      w0 = fmaf(v, Wc[k * 2 + 0], w0);
      w1 = fmaf(v, Wc[k * 2 + 1], w1);
    }
    Wf[t * 2 + 0] = w0;
    Wf[t * 2 + 1] = w1;
  }
  if (t < 2) {
    float s = bc[t];
    for (int k = 0; k < 128; ++k) s = fmaf(b2[k], Wc[k * 2 + t], s);
    bf[t] = s;
  }
}

// ---------- W1 -> bf16 transposed: W1Tg u32[j*64 + k/2] = {W1[k][j],W1[k+1][j]} ----
__global__ void w1t_kernel(const float* __restrict__ W1, unsigned* __restrict__ W1Tg) {
  int p = blockIdx.x * blockDim.x + threadIdx.x;  // 0..8191
  if (p >= 8192) return;
  int j = p >> 6;
  int kp = (p & 63) * 2;
  float a = W1[(size_t)kp * 128 + j];
  float b = W1[(size_t)(kp + 1) * 128 + j];
  W1Tg[p] = bf16rtn(a) | (bf16rtn(b) << 16);
}

// ---------- partition pass 1: per-(bin,block) histogram ----------
__global__ void histP_kernel(const int* __restrict__ dst, int* __restrict__ hist,
                             int E, unsigned multN) {
  __shared__ int h[NBIN];
  int t = threadIdx.x;
  for (int i = t; i < NBIN; i += blockDim.x) h[i] = 0;
  __syncthreads();
  int per = (E + PNB - 1) / PNB;
  int e0 = blockIdx.x * per, e1 = min(E, e0 + per);
  for (int e = e0 + t; e < e1; e += blockDim.x) {
    int b = __umulhi((unsigned)dst[e] * NBIN, multN);
    atomicAdd(&h[b], 1);
  }
  __syncthreads();
  for (int i = t; i < NBIN; i += blockDim.x) hist[i * PNB + blockIdx.x] = h[i];
}

// ---------- partition pass 2: exclusive scan of hist[NBIN*PNB] ----------
__global__ void scanP_kernel(int* __restrict__ hist, int* __restrict__ binstart, int E) {
  __shared__ int sh[256];
  int t = threadIdx.x;
  const int PER = (NBIN * PNB) / 256;  // 128
  int base = t * PER;
  int s = 0;
  for (int j = 0; j < PER; ++j) s += hist[base + j];
  sh[t] = s;
  __syncthreads();
  for (int off = 1; off < 256; off <<= 1) {
    int add = (t >= off) ? sh[t - off] : 0;
    __syncthreads();
    sh[t] += add;
    __syncthreads();
  }
  int run = sh[t] - s;  // exclusive
  for (int j = 0; j < PER; ++j) {
    int v = hist[base + j];
    hist[base + j] = run;
    int idx = base + j;
    if ((idx & (PNB - 1)) == 0) binstart[idx / PNB] = run;
    run += v;
  }
  if (t == 0) binstart[NBIN] = E;
}

// ---------- partition pass 3: scatter (src,dst) into reserved bin runs ----
__global__ void partP_kernel(const int* __restrict__ src, const int* __restrict__ dst,
                             const int* __restrict__ hist, int2* __restrict__ psd,
                             int E, unsigned multN) {
  __shared__ int cur[NBIN];
  int t = threadIdx.x;
  for (int i = t; i < NBIN; i += blockDim.x) cur[i] = hist[i * PNB + blockIdx.x];
  __syncthreads();
  int per = (E + PNB - 1) / PNB;
  int e0 = blockIdx.x * per, e1 = min(E, e0 + per);
  for (int e = e0 + t; e < e1; e += blockDim.x) {
    int d = dst[e];
    int s = src[e];
    int b = __umulhi((unsigned)d * NBIN, multN);
    int p = atomicAdd(&cur[b], 1);
    psd[p] = make_int2(s, d);
  }
}

// ---------- per-bin CSR build: degree count (LDS) -> scan -> offsets/counts/
//            dinv (coalesced) -> csr scatter inside private window ----------
__global__ __launch_bounds__(256) void csrbuild_kernel(
    const int2* __restrict__ psd, const int* __restrict__ binstart,
    int* __restrict__ offsets, int* __restrict__ counts, float* __restrict__ dinv,
    int* __restrict__ csr, int n, unsigned multN) {
  __shared__ int ldeg[1024];
  __shared__ int lcur[1024];
  __shared__ int sh[256];
  int b = blockIdx.x, t = threadIdx.x;
  unsigned long long denom = (unsigned long long)multN * NBIN;
  int lo = (int)((((unsigned long long)b << 32) + denom - 1) / denom);
  int hi = (int)((((unsigned long long)(b + 1) << 32) + denom - 1) / denom);
  if (hi > n) hi = n;
  if (lo > n) lo = n;
  int s0 = binstart[b], s1 = binstart[b + 1];
#pragma unroll
  for (int j = 0; j < 4; ++j) ldeg[t * 4 + j] = 0;
  __syncthreads();
  for (int e = s0 + t; e < s1; e += 256) atomicAdd(&ldeg[psd[e].y - lo], 1);
  __syncthreads();
  int c[4], loc = 0;
#pragma unroll
  for (int j = 0; j < 4; ++j) {
    c[j] = ldeg[t * 4 + j];
    loc += c[j];
  }
  sh[t] = loc;
  __syncthreads();
  for (int off = 1; off < 256; off <<= 1) {
    int add = (t >= off) ? sh[t - off] : 0;
    __syncthreads();
    sh[t] += add;
    __syncthreads();
  }
  int run = sh[t] - loc;  // exclusive
#pragma unroll
  for (int j = 0; j < 4; ++j) {
    int idx = t * 4 + j;
    lcur[idx] = run;
    int node = lo + idx;
    if (node < hi) {
      offsets[node] = s0 + run;
      counts[node] = c[j];
      dinv[node] = rsqrtf((float)(c[j] + 1));
    }
    run += c[j];
  }
  __syncthreads();
  for (int e = s0 + t; e < s1; e += 256) {
    int2 sd = psd[e];
    int p = atomicAdd(&lcur[sd.y - lo], 1);
    csr[s0 + p] = sd.x;
  }
}

// ---------- GEMM1 (MFMA): H1n = dinv[row] * ((x*sm) @ W1) in packed bf16 ----
__global__ __launch_bounds__(256) void gemm1_mfma_kernel(
    const float* __restrict__ x, const unsigned* __restrict__ W1Tg,
    const float* __restrict__ sm, const float* __restrict__ dinv,
    unsigned* __restrict__ H1n, int n) {
  __shared__ short lw1t[16384];  // 32 KB, W1T[j][k] bf16, swizzled
  __shared__ short lA[16384];    // 32 KB, A[r][k] bf16, swizzled
  __shared__ float ldv[128];
  int t = threadIdx.x;
  int rowbase = blockIdx.x * 128;

  if (t < 128) {
    int rg = rowbase + t;
    ldv[t] = (rg < n) ? dinv[rg] : 0.f;
  }
#pragma unroll
  for (int i = 0; i < 8; ++i) {
    int g = t + i * 256;
    int j = g >> 4;
    int c8 = (g & 15) * 8;
    uint4 v = *(const uint4*)(W1Tg + j * 64 + (c8 >> 1));
    int so = (j * 128 + c8) ^ ((j & 7) << 3);
    *(uint4*)(&lw1t[so]) = v;
  }
#pragma unroll
  for (int i = 0; i < 8; ++i) {
    int g = t + i * 256;
    int r = g >> 4;
    int c8 = (g & 15) * 8;
    int rowg = rowbase + r;
    uint4 p = {0, 0, 0, 0};
    if (rowg < n) {
      const float* xp = x + (size_t)rowg * 128 + c8;
      float4 xa = *(const float4*)(xp);
      float4 xb = *(const float4*)(xp + 4);
      float4 sa = *(const float4*)(sm + c8);
      float4 sb = *(const float4*)(sm + c8 + 4);
      p.x = bf16rtn(xa.x * sa.x) | (bf16rtn(xa.y * sa.y) << 16);
      p.y = bf16rtn(xa.z * sa.z) | (bf16rtn(xa.w * sa.w) << 16);
      p.z = bf16rtn(xb.x * sb.x) | (bf16rtn(xb.y * sb.y) << 16);
      p.w = bf16rtn(xb.z * sb.z) | (bf16rtn(xb.w * sb.w) << 16);
    }
    int so = (r * 128 + c8) ^ ((r & 7) << 3);
    *(uint4*)(&lA[so]) = p;
  }
  __syncthreads();

  int l = t & 63;
  int w = t >> 6;
  int wbase = w * 32;
  int lp = l & 31;
  int lhi = l >> 5;

  bf16x8 af[8];
#pragma unroll
  for (int kb = 0; kb < 8; ++kb) {
    int row = wbase + lp;
    int so = (row * 128 + kb * 16 + lhi * 8) ^ ((row & 7) << 3);
    af[kb] = *(const bf16x8*)(&lA[so]);
  }
  f32x16 acc0 = {}, acc1 = {}, acc2 = {}, acc3 = {};
#pragma unroll
  for (int kb = 0; kb < 8; ++kb) {
    int ko = kb * 16 + lhi * 8;
    int sw = (lp & 7) << 3;
    bf16x8 b0 = *(const bf16x8*)(&lw1t[((lp + 0) * 128 + ko) ^ sw]);
    bf16x8 b1 = *(const bf16x8*)(&lw1t[((lp + 32) * 128 + ko) ^ sw]);
    bf16x8 b2 = *(const bf16x8*)(&lw1t[((lp + 64) * 128 + ko) ^ sw]);
    bf16x8 b3 = *(const bf16x8*)(&lw1t[((lp + 96) * 128 + ko) ^ sw]);
    acc0 = __builtin_amdgcn_mfma_f32_32x32x16_bf16(af[kb], b0, acc0, 0, 0, 0);
    acc1 = __builtin_amdgcn_mfma_f32_32x32x16_bf16(af[kb], b1, acc1, 0, 0, 0);
    acc2 = __builtin_amdgcn_mfma_f32_32x32x16_bf16(af[kb], b2, acc2, 0, 0, 0);
    acc3 = __builtin_amdgcn_mfma_f32_32x32x16_bf16(af[kb], b3, acc3, 0, 0, 0);
  }

#pragma unroll
  for (int r = 0; r < 16; ++r) {
    int row_local = wbase + (r & 3) + 8 * (r >> 2) + 4 * lhi;
    float dv = ldv[row_local];
    int rowg = rowbase + row_local;
    bool ok = (rowg < n) && !(l & 1);
    size_t base = (size_t)rowg * 64 + (lp >> 1);
    {
      float v = acc0[r] * dv; float o = __shfl_xor(v, 1, 64);
      if (ok) H1n[base + 0] = bf16rtn(v) | (bf16rtn(o) << 16);
    }
    {
      float v = acc1[r] * dv; float o = __shfl_xor(v, 1, 64);
      if (ok) H1n[base + 16] = bf16rtn(v) | (bf16rtn(o) << 16);
    }
    {
      float v = acc2[r] * dv; float o = __shfl_xor(v, 1, 64);
      if (ok) H1n[base + 32] = bf16rtn(v) | (bf16rtn(o) << 16);
    }
    {
      float v = acc3[r] * dv; float o = __shfl_xor(v, 1, 64);
      if (ok) H1n[base + 48] = bf16rtn(v) | (bf16rtn(o) << 16);
    }
  }
}

// ---------- agg1 (wave per node): sum bf16 rows, h1 = relu(di*acc+b1),
//            Zn = di * (h1 @ Wf) ----------
__global__ __launch_bounds__(256) void agg1_kernel(
    const unsigned* __restrict__ H1n, const int* __restrict__ csr,
    const int* __restrict__ offsets, const int* __restrict__ counts,
    const float* __restrict__ dinv, const float* __restrict__ b1,
    const float* __restrict__ Wf, float* __restrict__ Zn, int n) {
  int lane = threadIdx.x & 63;
  int node = blockIdx.x * 4 + (threadIdx.x >> 6);
  if (node >= n) return;
  int c0 = lane * 2;

  float di = dinv[node];
  float2 acc = bf2unpack(H1n[(size_t)node * 64 + lane]);  // self-loop term

  int off = offsets[node];
  int cnt = counts[node];
  int e = 0;
  for (; e + 8 <= cnt; e += 8) {
    int s[8];
#pragma unroll
    for (int j = 0; j < 8; ++j) s[j] = csr[off + e + j];
    unsigned u[8];
#pragma unroll
    for (int j = 0; j < 8; ++j) u[j] = H1n[(size_t)s[j] * 64 + lane];
#pragma unroll
    for (int j = 0; j < 8; ++j) {
      float2 h = bf2unpack(u[j]);
      acc.x += h.x;
      acc.y += h.y;
    }
  }
  for (; e + 2 <= cnt; e += 2) {
    int s0 = csr[off + e], s1 = csr[off + e + 1];
    unsigned u0 = H1n[(size_t)s0 * 64 + lane];
    unsigned u1 = H1n[(size_t)s1 * 64 + lane];
    float2 h0 = bf2unpack(u0), h1v = bf2unpack(u1);
    acc.x += h0.x + h1v.x;
    acc.y += h0.y + h1v.y;
  }
  if (e < cnt) {
    int s0 = csr[off + e];
    float2 h0 = bf2unpack(H1n[(size_t)s0 * 64 + lane]);
    acc.x += h0.x;
    acc.y += h0.y;
  }

  float2 bb = *(const float2*)(b1 + c0);
  float v0 = fmaf(acc.x, di, bb.x); v0 = v0 > 0.f ? v0 : 0.f;
  float v1 = fmaf(acc.y, di, bb.y); v1 = v1 > 0.f ? v1 : 0.f;

  float4 wv = *(const float4*)(Wf + c0 * 2);
  float z0 = v0 * wv.x + v1 * wv.z;
  float z1 = v0 * wv.y + v1 * wv.w;
#pragma unroll
  for (int m = 32; m > 0; m >>= 1) {
    z0 += __shfl_xor(z0, m, 64);
    z1 += __shfl_xor(z1, m, 64);
  }
  if (lane == 0) {
    Zn[(size_t)node * 2 + 0] = z0 * di;
    Zn[(size_t)node * 2 + 1] = z1 * di;
  }
}

// ---------- agg2 (thread per node): out = di*(Zn[i] + sum Zn[s]) + bf ----------
__global__ void agg2_kernel(const float* __restrict__ Znb, const int* __restrict__ csr,
                            const int* __restrict__ offsets, const int* __restrict__ counts,
                            const float* __restrict__ dinv, const float* __restrict__ bf,
                            float* __restrict__ out, int n) {
  int i = blockIdx.x * blockDim.x + threadIdx.x;
  if (i >= n) return;
  float di = dinv[i];
  float2 z = *(const float2*)(Znb + (size_t)i * 2);
  float ax = z.x, ay = z.y;   // self-loop term
  int off = offsets[i], cnt = counts[i];
  for (int e = 0; e < cnt; ++e) {
    int s = csr[off + e];
    float2 zs = *(const float2*)(Znb + (size_t)s * 2);
    ax += zs.x;
    ay += zs.y;
  }
  out[(size_t)i * 2 + 0] = fmaf(ax, di, bf[0]);
  out[(size_t)i * 2 + 1] = fmaf(ay, di, bf[1]);
}

extern "C" void kernel_launch(void* const* d_in, const int* in_sizes, int n_in,
                              void* d_out, int out_size, void* d_ws, size_t ws_size,
                              hipStream_t stream) {
  const float* x = (const float*)d_in[0];
  const int* ei = (const int*)d_in[1];
  const float* fmask = (const float*)d_in[2];
  const float* W1 = (const float*)d_in[3];
  const float* b1 = (const float*)d_in[4];
  const float* W2 = (const float*)d_in[5];
  const float* b2 = (const float*)d_in[6];
  const float* Wc = (const float*)d_in[7];
  const float* bc = (const float*)d_in[8];

  int N = in_sizes[0] / 128;
  int E = in_sizes[1] / 2;
  const int* src = ei;
  const int* dst = ei + E;

  char* base = (char*)d_ws;
  size_t o = 0;
  auto take = [&](size_t bytes) -> char* {
    char* p = base + o;
    o = (o + bytes + 255) & ~(size_t)255;
    return p;
  };
  int* counts = (int*)take((size_t)N * 4);
  int* offsets = (int*)take((size_t)N * 4);
  float* dinv = (float*)take((size_t)N * 4);
  int* csr = (int*)take((size_t)E * 4);
  unsigned* H1n = (unsigned*)take((size_t)N * 64 * 4);  // packed bf16 rows
  float* Zn = (float*)take((size_t)N * 2 * 4);
  float* sm = (float*)take(128 * 4);
  float* Wf = (float*)take(256 * 4);
  float* bf = (float*)take(2 * 4);
  unsigned* W1Tg = (unsigned*)take(8192 * 4);           // W1^T bf16 packed
  int* hist = (int*)take((size_t)NBIN * PNB * 4);       // partition histogram
  int* binstart = (int*)take((NBIN + 1) * 4);
  int2* psd = (int2*)take((size_t)E * 8);               // partitioned (src,dst)
  (void)ws_size;
  (void)n_in;
  (void)out_size;

  // bin(d) = umulhi(d*NBIN, multN) ~ floor(d*NBIN/N); multN = ceil(2^32/N)
  unsigned multN = (unsigned)(((1ull << 32) + N - 1) / (unsigned long long)N);

  prep_kernel<<<1, 128, 0, stream>>>(fmask, W2, b2, Wc, bc, sm, Wf, bf);
  w1t_kernel<<<32, 256, 0, stream>>>(W1, W1Tg);
  histP_kernel<<<PNB, 256, 0, stream>>>(dst, hist, E, multN);
  scanP_kernel<<<1, 256, 0, stream>>>(hist, binstart, E);
  partP_kernel<<<PNB, 256, 0, stream>>>(src, dst, hist, psd, E, multN);
  csrbuild_kernel<<<NBIN, 256, 0, stream>>>(psd, binstart, offsets, counts, dinv, csr,
                                            N, multN);
  gemm1_mfma_kernel<<<(N + 127) / 128, 256, 0, stream>>>(x, W1Tg, sm, dinv, H1n, N);
  agg1_kernel<<<(N + 3) / 4, 256, 0, stream>>>(H1n, csr, offsets, counts, dinv, b1, Wf, Zn, N);
  agg2_kernel<<<(N + 255) / 256, 256, 0, stream>>>(Zn, csr, offsets, counts, dinv, bf,
                                                   (float*)d_out, N);
}

// Round 7
// 185.584 us; speedup vs baseline: 1.5110x; 1.0293x over previous
//
#include <hip/hip_runtime.h>
#include <math.h>

// ---------------------------------------------------------------------------
// GCN fraud-model forward:
//   out = A(relu(A(x*sig(mask) @ W1) + b1) @ (W2@Wc)) + (b2@Wc + bc)
// A-linearity folds W2@Wc -> [128,2].
//
// R3: dinv folded into stored rows; H1n stored packed bf16 (256B/row).
// R4: gemm1 -> MFMA bf16 32x32x16, XOR-swizzled LDS.
// R6: line-local CSR build: 128-bin partition + per-bin block builds CSR
//     slice in a private L2 window (fill write-amp gone).
// R7: agg1 is at the random-gather floor (26 cyc/edge = 10B/cyc/CU memory
//     ceiling, m13). Attack the other ~124us: NBIN 256 / PNB 128 doubles
//     csrbuild parallelism (128->256 blocks) and shrinks scanP 4x; prep+w1t
//     fused into one launch; agg1 gather unrolled 16-deep.
// ---------------------------------------------------------------------------

constexpr int NBIN = 256;  // partition bins (~391 nodes, ~6250 edges each)
constexpr int PNB = 128;   // histogram/scatter blocks

typedef __attribute__((ext_vector_type(8))) short bf16x8;
typedef __attribute__((ext_vector_type(16))) float f32x16;

__device__ __forceinline__ unsigned bf16rtn(float f) {
  unsigned b = __float_as_uint(f);
  b += 0x7FFFu + ((b >> 16) & 1u);   // round-to-nearest-even
  return b >> 16;
}
__device__ __forceinline__ float2 bf2unpack(unsigned u) {
  float2 r;
  r.x = __uint_as_float(u << 16);
  r.y = __uint_as_float(u & 0xFFFF0000u);
  return r;
}

// ---------- fused prep (block 0) + W1 transpose->bf16 (blocks 1..32) ----------
__global__ void prep_w1t_kernel(const float* __restrict__ fmask, const float* __restrict__ W2,
                                const float* __restrict__ b2, const float* __restrict__ Wc,
                                const float* __restrict__ bc, const float* __restrict__ W1,
                                float* __restrict__ sm, float* __restrict__ Wf,
                                float* __restrict__ bf, unsigned* __restrict__ W1Tg) {
  int t = threadIdx.x;
  if (blockIdx.x == 0) {
    if (t < 128) {
      sm[t] = 1.0f / (1.0f + expf(-fmask[t]));
      float w0 = 0.f, w1 = 0.f;
      for (int k = 0; k < 128; ++k) {
        float v = W2[t * 128 + k];
        w0 = fmaf(v, Wc[k * 2 + 0], w0);
        w1 = fmaf(v, Wc[k * 2 + 1], w1);
      }
      Wf[t * 2 + 0] = w0;
      Wf[t * 2 + 1] = w1;
    }
    if (t >= 128 && t < 130) {
      int j = t - 128;
      float s = bc[j];
      for (int k = 0; k < 128; ++k) s = fmaf(b2[k], Wc[k * 2 + j], s);
      bf[j] = s;
    }
  } else {
    int p = (blockIdx.x - 1) * 256 + t;  // 0..8191
    if (p < 8192) {
      int j = p >> 6;
      int kp = (p & 63) * 2;
      float a = W1[(size_t)kp * 128 + j];
      float b = W1[(size_t)(kp + 1) * 128 + j];
      W1Tg[p] = bf16rtn(a) | (bf16rtn(b) << 16);
    }
  }
}

// ---------- partition pass 1: per-(bin,block) histogram ----------
__global__ void histP_kernel(const int* __restrict__ dst, int* __restrict__ hist,
                             int E, unsigned multN) {
  __shared__ int h[NBIN];
  int t = threadIdx.x;
  for (int i = t; i < NBIN; i += blockDim.x) h[i] = 0;
  __syncthreads();
  int per = (E + PNB - 1) / PNB;
  int e0 = blockIdx.x * per, e1 = min(E, e0 + per);
  for (int e = e0 + t; e < e1; e += blockDim.x) {
    int b = __umulhi((unsigned)dst[e] * NBIN, multN);
    atomicAdd(&h[b], 1);
  }
  __syncthreads();
  for (int i = t; i < NBIN; i += blockDim.x) hist[i * PNB + blockIdx.x] = h[i];
}

// ---------- partition pass 2: exclusive scan of hist[NBIN*PNB] ----------
__global__ void scanP_kernel(int* __restrict__ hist, int* __restrict__ binstart, int E) {
  __shared__ int sh[256];
  int t = threadIdx.x;
  const int PER = (NBIN * PNB) / 256;  // 128
  int base = t * PER;
  int s = 0;
  for (int j = 0; j < PER; ++j) s += hist[base + j];
  sh[t] = s;
  __syncthreads();
  for (int off = 1; off < 256; off <<= 1) {
    int add = (t >= off) ? sh[t - off] : 0;
    __syncthreads();
    sh[t] += add;
    __syncthreads();
  }
  int run = sh[t] - s;  // exclusive
  for (int j = 0; j < PER; ++j) {
    int v = hist[base + j];
    hist[base + j] = run;
    int idx = base + j;
    if ((idx & (PNB - 1)) == 0) binstart[idx / PNB] = run;
    run += v;
  }
  if (t == 0) binstart[NBIN] = E;
}

// ---------- partition pass 3: scatter (src,dst) into reserved bin runs ----
__global__ void partP_kernel(const int* __restrict__ src, const int* __restrict__ dst,
                             const int* __restrict__ hist, int2* __restrict__ psd,
                             int E, unsigned multN) {
  __shared__ int cur[NBIN];
  int t = threadIdx.x;
  for (int i = t; i < NBIN; i += blockDim.x) cur[i] = hist[i * PNB + blockIdx.x];
  __syncthreads();
  int per = (E + PNB - 1) / PNB;
  int e0 = blockIdx.x * per, e1 = min(E, e0 + per);
  for (int e = e0 + t; e < e1; e += blockDim.x) {
    int d = dst[e];
    int s = src[e];
    int b = __umulhi((unsigned)d * NBIN, multN);
    int p = atomicAdd(&cur[b], 1);
    psd[p] = make_int2(s, d);
  }
}

// ---------- per-bin CSR build: degree count (LDS) -> scan -> offsets/counts/
//            dinv (coalesced) -> csr scatter inside private window ----------
__global__ __launch_bounds__(256) void csrbuild_kernel(
    const int2* __restrict__ psd, const int* __restrict__ binstart,
    int* __restrict__ offsets, int* __restrict__ counts, float* __restrict__ dinv,
    int* __restrict__ csr, int n, unsigned multN) {
  __shared__ int ldeg[512];
  __shared__ int lcur[512];
  __shared__ int sh[256];
  int b = blockIdx.x, t = threadIdx.x;
  unsigned long long denom = (unsigned long long)multN * NBIN;
  int lo = (int)((((unsigned long long)b << 32) + denom - 1) / denom);
  int hi = (int)((((unsigned long long)(b + 1) << 32) + denom - 1) / denom);
  if (hi > n) hi = n;
  if (lo > n) lo = n;
  int s0 = binstart[b], s1 = binstart[b + 1];
#pragma unroll
  for (int j = 0; j < 2; ++j) ldeg[t * 2 + j] = 0;
  __syncthreads();
  for (int e = s0 + t; e < s1; e += 256) atomicAdd(&ldeg[psd[e].y - lo], 1);
  __syncthreads();
  int c[2], loc = 0;
#pragma unroll
  for (int j = 0; j < 2; ++j) {
    c[j] = ldeg[t * 2 + j];
    loc += c[j];
  }
  sh[t] = loc;
  __syncthreads();
  for (int off = 1; off < 256; off <<= 1) {
    int add = (t >= off) ? sh[t - off] : 0;
    __syncthreads();
    sh[t] += add;
    __syncthreads();
  }
  int run = sh[t] - loc;  // exclusive
#pragma unroll
  for (int j = 0; j < 2; ++j) {
    int idx = t * 2 + j;
    lcur[idx] = run;
    int node = lo + idx;
    if (node < hi) {
      offsets[node] = s0 + run;
      counts[node] = c[j];
      dinv[node] = rsqrtf((float)(c[j] + 1));
    }
    run += c[j];
  }
  __syncthreads();
  for (int e = s0 + t; e < s1; e += 256) {
    int2 sd = psd[e];
    int p = atomicAdd(&lcur[sd.y - lo], 1);
    csr[s0 + p] = sd.x;
  }
}

// ---------- GEMM1 (MFMA): H1n = dinv[row] * ((x*sm) @ W1) in packed bf16 ----
__global__ __launch_bounds__(256) void gemm1_mfma_kernel(
    const float* __restrict__ x, const unsigned* __restrict__ W1Tg,
    const float* __restrict__ sm, const float* __restrict__ dinv,
    unsigned* __restrict__ H1n, int n) {
  __shared__ short lw1t[16384];  // 32 KB, W1T[j][k] bf16, swizzled
  __shared__ short lA[16384];    // 32 KB, A[r][k] bf16, swizzled
  __shared__ float ldv[128];
  int t = threadIdx.x;
  int rowbase = blockIdx.x * 128;

  if (t < 128) {
    int rg = rowbase + t;
    ldv[t] = (rg < n) ? dinv[rg] : 0.f;
  }
#pragma unroll
  for (int i = 0; i < 8; ++i) {
    int g = t + i * 256;
    int j = g >> 4;
    int c8 = (g & 15) * 8;
    uint4 v = *(const uint4*)(W1Tg + j * 64 + (c8 >> 1));
    int so = (j * 128 + c8) ^ ((j & 7) << 3);
    *(uint4*)(&lw1t[so]) = v;
  }
#pragma unroll
  for (int i = 0; i < 8; ++i) {
    int g = t + i * 256;
    int r = g >> 4;
    int c8 = (g & 15) * 8;
    int rowg = rowbase + r;
    uint4 p = {0, 0, 0, 0};
    if (rowg < n) {
      const float* xp = x + (size_t)rowg * 128 + c8;
      float4 xa = *(const float4*)(xp);
      float4 xb = *(const float4*)(xp + 4);
      float4 sa = *(const float4*)(sm + c8);
      float4 sb = *(const float4*)(sm + c8 + 4);
      p.x = bf16rtn(xa.x * sa.x) | (bf16rtn(xa.y * sa.y) << 16);
      p.y = bf16rtn(xa.z * sa.z) | (bf16rtn(xa.w * sa.w) << 16);
      p.z = bf16rtn(xb.x * sb.x) | (bf16rtn(xb.y * sb.y) << 16);
      p.w = bf16rtn(xb.z * sb.z) | (bf16rtn(xb.w * sb.w) << 16);
    }
    int so = (r * 128 + c8) ^ ((r & 7) << 3);
    *(uint4*)(&lA[so]) = p;
  }
  __syncthreads();

  int l = t & 63;
  int w = t >> 6;
  int wbase = w * 32;
  int lp = l & 31;
  int lhi = l >> 5;

  bf16x8 af[8];
#pragma unroll
  for (int kb = 0; kb < 8; ++kb) {
    int row = wbase + lp;
    int so = (row * 128 + kb * 16 + lhi * 8) ^ ((row & 7) << 3);
    af[kb] = *(const bf16x8*)(&lA[so]);
  }
  f32x16 acc0 = {}, acc1 = {}, acc2 = {}, acc3 = {};
#pragma unroll
  for (int kb = 0; kb < 8; ++kb) {
    int ko = kb * 16 + lhi * 8;
    int sw = (lp & 7) << 3;
    bf16x8 b0 = *(const bf16x8*)(&lw1t[((lp + 0) * 128 + ko) ^ sw]);
    bf16x8 b1 = *(const bf16x8*)(&lw1t[((lp + 32) * 128 + ko) ^ sw]);
    bf16x8 b2 = *(const bf16x8*)(&lw1t[((lp + 64) * 128 + ko) ^ sw]);
    bf16x8 b3 = *(const bf16x8*)(&lw1t[((lp + 96) * 128 + ko) ^ sw]);
    acc0 = __builtin_amdgcn_mfma_f32_32x32x16_bf16(af[kb], b0, acc0, 0, 0, 0);
    acc1 = __builtin_amdgcn_mfma_f32_32x32x16_bf16(af[kb], b1, acc1, 0, 0, 0);
    acc2 = __builtin_amdgcn_mfma_f32_32x32x16_bf16(af[kb], b2, acc2, 0, 0, 0);
    acc3 = __builtin_amdgcn_mfma_f32_32x32x16_bf16(af[kb], b3, acc3, 0, 0, 0);
  }

#pragma unroll
  for (int r = 0; r < 16; ++r) {
    int row_local = wbase + (r & 3) + 8 * (r >> 2) + 4 * lhi;
    float dv = ldv[row_local];
    int rowg = rowbase + row_local;
    bool ok = (rowg < n) && !(l & 1);
    size_t base = (size_t)rowg * 64 + (lp >> 1);
    {
      float v = acc0[r] * dv; float o = __shfl_xor(v, 1, 64);
      if (ok) H1n[base + 0] = bf16rtn(v) | (bf16rtn(o) << 16);
    }
    {
      float v = acc1[r] * dv; float o = __shfl_xor(v, 1, 64);
      if (ok) H1n[base + 16] = bf16rtn(v) | (bf16rtn(o) << 16);
    }
    {
      float v = acc2[r] * dv; float o = __shfl_xor(v, 1, 64);
      if (ok) H1n[base + 32] = bf16rtn(v) | (bf16rtn(o) << 16);
    }
    {
      float v = acc3[r] * dv; float o = __shfl_xor(v, 1, 64);
      if (ok) H1n[base + 48] = bf16rtn(v) | (bf16rtn(o) << 16);
    }
  }
}

// ---------- agg1 (wave per node): sum bf16 rows, h1 = relu(di*acc+b1),
//            Zn = di * (h1 @ Wf) ----------
__global__ __launch_bounds__(256) void agg1_kernel(
    const unsigned* __restrict__ H1n, const int* __restrict__ csr,
    const int* __restrict__ offsets, const int* __restrict__ counts,
    const float* __restrict__ dinv, const float* __restrict__ b1,
    const float* __restrict__ Wf, float* __restrict__ Zn, int n) {
  int lane = threadIdx.x & 63;
  int node = blockIdx.x * 4 + (threadIdx.x >> 6);
  if (node >= n) return;
  int c0 = lane * 2;

  float di = dinv[node];
  float2 acc = bf2unpack(H1n[(size_t)node * 64 + lane]);  // self-loop term

  int off = offsets[node];
  int cnt = counts[node];
  int e = 0;
  for (; e + 16 <= cnt; e += 16) {
    int s[16];
#pragma unroll
    for (int j = 0; j < 16; ++j) s[j] = csr[off + e + j];
    unsigned u[16];
#pragma unroll
    for (int j = 0; j < 16; ++j) u[j] = H1n[(size_t)s[j] * 64 + lane];
#pragma unroll
    for (int j = 0; j < 16; ++j) {
      float2 h = bf2unpack(u[j]);
      acc.x += h.x;
      acc.y += h.y;
    }
  }
  for (; e + 4 <= cnt; e += 4) {
    int s[4];
#pragma unroll
    for (int j = 0; j < 4; ++j) s[j] = csr[off + e + j];
    unsigned u[4];
#pragma unroll
    for (int j = 0; j < 4; ++j) u[j] = H1n[(size_t)s[j] * 64 + lane];
#pragma unroll
    for (int j = 0; j < 4; ++j) {
      float2 h = bf2unpack(u[j]);
      acc.x += h.x;
      acc.y += h.y;
    }
  }
  for (; e < cnt; ++e) {
    int s0 = csr[off + e];
    float2 h0 = bf2unpack(H1n[(size_t)s0 * 64 + lane]);
    acc.x += h0.x;
    acc.y += h0.y;
  }

  float2 bb = *(const float2*)(b1 + c0);
  float v0 = fmaf(acc.x, di, bb.x); v0 = v0 > 0.f ? v0 : 0.f;
  float v1 = fmaf(acc.y, di, bb.y); v1 = v1 > 0.f ? v1 : 0.f;

  float4 wv = *(const float4*)(Wf + c0 * 2);
  float z0 = v0 * wv.x + v1 * wv.z;
  float z1 = v0 * wv.y + v1 * wv.w;
#pragma unroll
  for (int m = 32; m > 0; m >>= 1) {
    z0 += __shfl_xor(z0, m, 64);
    z1 += __shfl_xor(z1, m, 64);
  }
  if (lane == 0) {
    Zn[(size_t)node * 2 + 0] = z0 * di;
    Zn[(size_t)node * 2 + 1] = z1 * di;
  }
}

// ---------- agg2 (thread per node): out = di*(Zn[i] + sum Zn[s]) + bf ----------
__global__ void agg2_kernel(const float* __restrict__ Znb, const int* __restrict__ csr,
                            const int* __restrict__ offsets, const int* __restrict__ counts,
                            const float* __restrict__ dinv, const float* __restrict__ bf,
                            float* __restrict__ out, int n) {
  int i = blockIdx.x * blockDim.x + threadIdx.x;
  if (i >= n) return;
  float di = dinv[i];
  float2 z = *(const float2*)(Znb + (size_t)i * 2);
  float ax = z.x, ay = z.y;   // self-loop term
  int off = offsets[i], cnt = counts[i];
  for (int e = 0; e < cnt; ++e) {
    int s = csr[off + e];
    float2 zs = *(const float2*)(Znb + (size_t)s * 2);
    ax += zs.x;
    ay += zs.y;
  }
  out[(size_t)i * 2 + 0] = fmaf(ax, di, bf[0]);
  out[(size_t)i * 2 + 1] = fmaf(ay, di, bf[1]);
}

extern "C" void kernel_launch(void* const* d_in, const int* in_sizes, int n_in,
                              void* d_out, int out_size, void* d_ws, size_t ws_size,
                              hipStream_t stream) {
  const float* x = (const float*)d_in[0];
  const int* ei = (const int*)d_in[1];
  const float* fmask = (const float*)d_in[2];
  const float* W1 = (const float*)d_in[3];
  const float* b1 = (const float*)d_in[4];
  const float* W2 = (const float*)d_in[5];
  const float* b2 = (const float*)d_in[6];
  const float* Wc = (const float*)d_in[7];
  const float* bc = (const float*)d_in[8];

  int N = in_sizes[0] / 128;
  int E = in_sizes[1] / 2;
  const int* src = ei;
  const int* dst = ei + E;

  char* base = (char*)d_ws;
  size_t o = 0;
  auto take = [&](size_t bytes) -> char* {
    char* p = base + o;
    o = (o + bytes + 255) & ~(size_t)255;
    return p;
  };
  int* counts = (int*)take((size_t)N * 4);
  int* offsets = (int*)take((size_t)N * 4);
  float* dinv = (float*)take((size_t)N * 4);
  int* csr = (int*)take((size_t)E * 4);
  unsigned* H1n = (unsigned*)take((size_t)N * 64 * 4);  // packed bf16 rows
  float* Zn = (float*)take((size_t)N * 2 * 4);
  float* sm = (float*)take(128 * 4);
  float* Wf = (float*)take(256 * 4);
  float* bf = (float*)take(2 * 4);
  unsigned* W1Tg = (unsigned*)take(8192 * 4);           // W1^T bf16 packed
  int* hist = (int*)take((size_t)NBIN * PNB * 4);       // partition histogram
  int* binstart = (int*)take((NBIN + 1) * 4);
  int2* psd = (int2*)take((size_t)E * 8);               // partitioned (src,dst)
  (void)ws_size;
  (void)n_in;
  (void)out_size;

  // bin(d) = umulhi(d*NBIN, multN) ~ floor(d*NBIN/N); multN = ceil(2^32/N)
  unsigned multN = (unsigned)(((1ull << 32) + N - 1) / (unsigned long long)N);

  prep_w1t_kernel<<<33, 256, 0, stream>>>(fmask, W2, b2, Wc, bc, W1, sm, Wf, bf, W1Tg);
  histP_kernel<<<PNB, 256, 0, stream>>>(dst, hist, E, multN);
  scanP_kernel<<<1, 256, 0, stream>>>(hist, binstart, E);
  partP_kernel<<<PNB, 256, 0, stream>>>(src, dst, hist, psd, E, multN);
  csrbuild_kernel<<<NBIN, 256, 0, stream>>>(psd, binstart, offsets, counts, dinv, csr,
                                            N, multN);
  gemm1_mfma_kernel<<<(N + 127) / 128, 256, 0, stream>>>(x, W1Tg, sm, dinv, H1n, N);
  agg1_kernel<<<(N + 3) / 4, 256, 0, stream>>>(H1n, csr, offsets, counts, dinv, b1, Wf, Zn, N);
  agg2_kernel<<<(N + 255) / 256, 256, 0, stream>>>(Zn, csr, offsets, counts, dinv, bf,
                                                   (float*)d_out, N);
}

// Round 8
// 171.128 us; speedup vs baseline: 1.6386x; 1.0845x over previous
//
#include <hip/hip_runtime.h>
#include <math.h>

// ---------------------------------------------------------------------------
// GCN fraud-model forward:
//   out = A(relu(A(x*sig(mask) @ W1) + b1) @ (W2@Wc)) + (b2@Wc + bc)
// A-linearity folds W2@Wc -> [128,2].
//
// R3: dinv folded into stored rows; H1n stored packed bf16 (256B/row).
// R4: gemm1 -> MFMA bf16 32x32x16, XOR-swizzled LDS.
// R6: line-local CSR build (bin partition + per-bin block; write-amp gone).
// R7: NBIN=256, fused prep, agg1 at random-gather floor (190MB FETCH).
// R8: edge chain slimmed: partitioned edge packed to ONE u32
//     (src | local_d<<20; src<2^20, local_d<2^12) -> partP/csrbuild traffic
//     -19MB; agg1/agg2 index streams scalarized via readfirstlane (uniform
//     offsets/counts -> s_load, halves VMEM issue); agg2 4-deep unroll;
//     prep+w1t fused into histP (one less launch).
// ---------------------------------------------------------------------------

constexpr int NBIN = 256;  // partition bins (~391 nodes, ~6250 edges each)
constexpr int PNB = 128;   // histogram/scatter blocks

typedef __attribute__((ext_vector_type(8))) short bf16x8;
typedef __attribute__((ext_vector_type(16))) float f32x16;

__device__ __forceinline__ unsigned bf16rtn(float f) {
  unsigned b = __float_as_uint(f);
  b += 0x7FFFu + ((b >> 16) & 1u);   // round-to-nearest-even
  return b >> 16;
}
__device__ __forceinline__ float2 bf2unpack(unsigned u) {
  float2 r;
  r.x = __uint_as_float(u << 16);
  r.y = __uint_as_float(u & 0xFFFF0000u);
  return r;
}

// ---------- fused: hist (blocks 0..PNB-1) + prep (PNB) + w1t (PNB+1..) ------
__global__ void histP_prep_kernel(const int* __restrict__ dst, int* __restrict__ hist,
                                  int E, unsigned multN,
                                  const float* __restrict__ fmask, const float* __restrict__ W2,
                                  const float* __restrict__ b2, const float* __restrict__ Wc,
                                  const float* __restrict__ bc, const float* __restrict__ W1,
                                  float* __restrict__ sm, float* __restrict__ Wf,
                                  float* __restrict__ bf, unsigned* __restrict__ W1Tg) {
  int t = threadIdx.x;
  if (blockIdx.x >= PNB) {
    int bb = blockIdx.x - PNB;
    if (bb == 0) {
      if (t < 128) {
        sm[t] = 1.0f / (1.0f + expf(-fmask[t]));
        float w0 = 0.f, w1 = 0.f;
        for (int k = 0; k < 128; ++k) {
          float v = W2[t * 128 + k];
          w0 = fmaf(v, Wc[k * 2 + 0], w0);
          w1 = fmaf(v, Wc[k * 2 + 1], w1);
        }
        Wf[t * 2 + 0] = w0;
        Wf[t * 2 + 1] = w1;
      }
      if (t >= 128 && t < 130) {
        int j = t - 128;
        float s = bc[j];
        for (int k = 0; k < 128; ++k) s = fmaf(b2[k], Wc[k * 2 + j], s);
        bf[j] = s;
      }
    } else {
      int p = (bb - 1) * 256 + t;  // 0..8191
      if (p < 8192) {
        int j = p >> 6;
        int kp = (p & 63) * 2;
        float a = W1[(size_t)kp * 128 + j];
        float b = W1[(size_t)(kp + 1) * 128 + j];
        W1Tg[p] = bf16rtn(a) | (bf16rtn(b) << 16);
      }
    }
    return;
  }
  __shared__ int h[NBIN];
  for (int i = t; i < NBIN; i += blockDim.x) h[i] = 0;
  __syncthreads();
  int per = (E + PNB - 1) / PNB;
  int e0 = blockIdx.x * per, e1 = min(E, e0 + per);
  for (int e = e0 + t; e < e1; e += blockDim.x) {
    int b = __umulhi((unsigned)dst[e] * NBIN, multN);
    atomicAdd(&h[b], 1);
  }
  __syncthreads();
  for (int i = t; i < NBIN; i += blockDim.x) hist[i * PNB + blockIdx.x] = h[i];
}

// ---------- partition pass 2: exclusive scan of hist[NBIN*PNB] ----------
__global__ void scanP_kernel(int* __restrict__ hist, int* __restrict__ binstart, int E) {
  __shared__ int sh[256];
  int t = threadIdx.x;
  const int PER = (NBIN * PNB) / 256;  // 128
  int base = t * PER;
  int s = 0;
  for (int j = 0; j < PER; ++j) s += hist[base + j];
  sh[t] = s;
  __syncthreads();
  for (int off = 1; off < 256; off <<= 1) {
    int add = (t >= off) ? sh[t - off] : 0;
    __syncthreads();
    sh[t] += add;
    __syncthreads();
  }
  int run = sh[t] - s;  // exclusive
  for (int j = 0; j < PER; ++j) {
    int v = hist[base + j];
    hist[base + j] = run;
    int idx = base + j;
    if ((idx & (PNB - 1)) == 0) binstart[idx / PNB] = run;
    run += v;
  }
  if (t == 0) binstart[NBIN] = E;
}

// ---------- partition pass 3: scatter packed (src | local_d<<20) ----------
__global__ void partP_kernel(const int* __restrict__ src, const int* __restrict__ dst,
                             const int* __restrict__ hist, unsigned* __restrict__ psd,
                             int E, unsigned multN) {
  __shared__ int cur[NBIN];
  __shared__ int llo[NBIN];
  int t = threadIdx.x;
  unsigned long long denom = (unsigned long long)multN * NBIN;
  for (int i = t; i < NBIN; i += blockDim.x) {
    cur[i] = hist[i * PNB + blockIdx.x];
    llo[i] = (int)((((unsigned long long)i << 32) + denom - 1) / denom);
  }
  __syncthreads();
  int per = (E + PNB - 1) / PNB;
  int e0 = blockIdx.x * per, e1 = min(E, e0 + per);
  for (int e = e0 + t; e < e1; e += blockDim.x) {
    int d = dst[e];
    int s = src[e];
    int b = __umulhi((unsigned)d * NBIN, multN);
    int p = atomicAdd(&cur[b], 1);
    psd[p] = (unsigned)s | ((unsigned)(d - llo[b]) << 20);
  }
}

// ---------- per-bin CSR build from packed edges ----------
__global__ __launch_bounds__(256) void csrbuild_kernel(
    const unsigned* __restrict__ psd, const int* __restrict__ binstart,
    int* __restrict__ offsets, int* __restrict__ counts, float* __restrict__ dinv,
    int* __restrict__ csr, int n, unsigned multN) {
  __shared__ int ldeg[512];
  __shared__ int lcur[512];
  __shared__ int sh[256];
  int b = blockIdx.x, t = threadIdx.x;
  unsigned long long denom = (unsigned long long)multN * NBIN;
  int lo = (int)((((unsigned long long)b << 32) + denom - 1) / denom);
  int hi = (int)((((unsigned long long)(b + 1) << 32) + denom - 1) / denom);
  if (hi > n) hi = n;
  if (lo > n) lo = n;
  int s0 = binstart[b], s1 = binstart[b + 1];
#pragma unroll
  for (int j = 0; j < 2; ++j) ldeg[t * 2 + j] = 0;
  __syncthreads();
  for (int e = s0 + t; e < s1; e += 256) atomicAdd(&ldeg[psd[e] >> 20], 1);
  __syncthreads();
  int c[2], loc = 0;
#pragma unroll
  for (int j = 0; j < 2; ++j) {
    c[j] = ldeg[t * 2 + j];
    loc += c[j];
  }
  sh[t] = loc;
  __syncthreads();
  for (int off = 1; off < 256; off <<= 1) {
    int add = (t >= off) ? sh[t - off] : 0;
    __syncthreads();
    sh[t] += add;
    __syncthreads();
  }
  int run = sh[t] - loc;  // exclusive
#pragma unroll
  for (int j = 0; j < 2; ++j) {
    int idx = t * 2 + j;
    lcur[idx] = run;
    int node = lo + idx;
    if (node < hi) {
      offsets[node] = s0 + run;
      counts[node] = c[j];
      dinv[node] = rsqrtf((float)(c[j] + 1));
    }
    run += c[j];
  }
  __syncthreads();
  for (int e = s0 + t; e < s1; e += 256) {
    unsigned pd = psd[e];
    int p = atomicAdd(&lcur[pd >> 20], 1);
    csr[s0 + p] = (int)(pd & 0xFFFFFu);
  }
}

// ---------- GEMM1 (MFMA): H1n = dinv[row] * ((x*sm) @ W1) in packed bf16 ----
__global__ __launch_bounds__(256) void gemm1_mfma_kernel(
    const float* __restrict__ x, const unsigned* __restrict__ W1Tg,
    const float* __restrict__ sm, const float* __restrict__ dinv,
    unsigned* __restrict__ H1n, int n) {
  __shared__ short lw1t[16384];  // 32 KB, W1T[j][k] bf16, swizzled
  __shared__ short lA[16384];    // 32 KB, A[r][k] bf16, swizzled
  __shared__ float ldv[128];
  int t = threadIdx.x;
  int rowbase = blockIdx.x * 128;

  if (t < 128) {
    int rg = rowbase + t;
    ldv[t] = (rg < n) ? dinv[rg] : 0.f;
  }
#pragma unroll
  for (int i = 0; i < 8; ++i) {
    int g = t + i * 256;
    int j = g >> 4;
    int c8 = (g & 15) * 8;
    uint4 v = *(const uint4*)(W1Tg + j * 64 + (c8 >> 1));
    int so = (j * 128 + c8) ^ ((j & 7) << 3);
    *(uint4*)(&lw1t[so]) = v;
  }
#pragma unroll
  for (int i = 0; i < 8; ++i) {
    int g = t + i * 256;
    int r = g >> 4;
    int c8 = (g & 15) * 8;
    int rowg = rowbase + r;
    uint4 p = {0, 0, 0, 0};
    if (rowg < n) {
      const float* xp = x + (size_t)rowg * 128 + c8;
      float4 xa = *(const float4*)(xp);
      float4 xb = *(const float4*)(xp + 4);
      float4 sa = *(const float4*)(sm + c8);
      float4 sb = *(const float4*)(sm + c8 + 4);
      p.x = bf16rtn(xa.x * sa.x) | (bf16rtn(xa.y * sa.y) << 16);
      p.y = bf16rtn(xa.z * sa.z) | (bf16rtn(xa.w * sa.w) << 16);
      p.z = bf16rtn(xb.x * sb.x) | (bf16rtn(xb.y * sb.y) << 16);
      p.w = bf16rtn(xb.z * sb.z) | (bf16rtn(xb.w * sb.w) << 16);
    }
    int so = (r * 128 + c8) ^ ((r & 7) << 3);
    *(uint4*)(&lA[so]) = p;
  }
  __syncthreads();

  int l = t & 63;
  int w = t >> 6;
  int wbase = w * 32;
  int lp = l & 31;
  int lhi = l >> 5;

  bf16x8 af[8];
#pragma unroll
  for (int kb = 0; kb < 8; ++kb) {
    int row = wbase + lp;
    int so = (row * 128 + kb * 16 + lhi * 8) ^ ((row & 7) << 3);
    af[kb] = *(const bf16x8*)(&lA[so]);
  }
  f32x16 acc0 = {}, acc1 = {}, acc2 = {}, acc3 = {};
#pragma unroll
  for (int kb = 0; kb < 8; ++kb) {
    int ko = kb * 16 + lhi * 8;
    int sw = (lp & 7) << 3;
    bf16x8 b0 = *(const bf16x8*)(&lw1t[((lp + 0) * 128 + ko) ^ sw]);
    bf16x8 b1 = *(const bf16x8*)(&lw1t[((lp + 32) * 128 + ko) ^ sw]);
    bf16x8 b2 = *(const bf16x8*)(&lw1t[((lp + 64) * 128 + ko) ^ sw]);
    bf16x8 b3 = *(const bf16x8*)(&lw1t[((lp + 96) * 128 + ko) ^ sw]);
    acc0 = __builtin_amdgcn_mfma_f32_32x32x16_bf16(af[kb], b0, acc0, 0, 0, 0);
    acc1 = __builtin_amdgcn_mfma_f32_32x32x16_bf16(af[kb], b1, acc1, 0, 0, 0);
    acc2 = __builtin_amdgcn_mfma_f32_32x32x16_bf16(af[kb], b2, acc2, 0, 0, 0);
    acc3 = __builtin_amdgcn_mfma_f32_32x32x16_bf16(af[kb], b3, acc3, 0, 0, 0);
  }

#pragma unroll
  for (int r = 0; r < 16; ++r) {
    int row_local = wbase + (r & 3) + 8 * (r >> 2) + 4 * lhi;
    float dv = ldv[row_local];
    int rowg = rowbase + row_local;
    bool ok = (rowg < n) && !(l & 1);
    size_t base = (size_t)rowg * 64 + (lp >> 1);
    {
      float v = acc0[r] * dv; float o = __shfl_xor(v, 1, 64);
      if (ok) H1n[base + 0] = bf16rtn(v) | (bf16rtn(o) << 16);
    }
    {
      float v = acc1[r] * dv; float o = __shfl_xor(v, 1, 64);
      if (ok) H1n[base + 16] = bf16rtn(v) | (bf16rtn(o) << 16);
    }
    {
      float v = acc2[r] * dv; float o = __shfl_xor(v, 1, 64);
      if (ok) H1n[base + 32] = bf16rtn(v) | (bf16rtn(o) << 16);
    }
    {
      float v = acc3[r] * dv; float o = __shfl_xor(v, 1, 64);
      if (ok) H1n[base + 48] = bf16rtn(v) | (bf16rtn(o) << 16);
    }
  }
}

// ---------- agg1 (wave per node): sum bf16 rows, h1 = relu(di*acc+b1),
//            Zn = di * (h1 @ Wf). Index stream scalarized. ----------
__global__ __launch_bounds__(256) void agg1_kernel(
    const unsigned* __restrict__ H1n, const int* __restrict__ csr,
    const int* __restrict__ offsets, const int* __restrict__ counts,
    const float* __restrict__ dinv, const float* __restrict__ b1,
    const float* __restrict__ Wf, float* __restrict__ Zn, int n) {
  int lane = threadIdx.x & 63;
  int node = blockIdx.x * 4 + (threadIdx.x >> 6);
  if (node >= n) return;
  int c0 = lane * 2;

  float di = dinv[node];
  float2 acc = bf2unpack(H1n[(size_t)node * 64 + lane]);  // self-loop term

  int off = __builtin_amdgcn_readfirstlane(offsets[node]);
  int cnt = __builtin_amdgcn_readfirstlane(counts[node]);
  int e = 0;
  for (; e + 16 <= cnt; e += 16) {
    int s[16];
#pragma unroll
    for (int j = 0; j < 16; ++j) s[j] = __builtin_amdgcn_readfirstlane(csr[off + e + j]);
    unsigned u[16];
#pragma unroll
    for (int j = 0; j < 16; ++j) u[j] = H1n[(size_t)s[j] * 64 + lane];
#pragma unroll
    for (int j = 0; j < 16; ++j) {
      float2 h = bf2unpack(u[j]);
      acc.x += h.x;
      acc.y += h.y;
    }
  }
  for (; e + 4 <= cnt; e += 4) {
    int s[4];
#pragma unroll
    for (int j = 0; j < 4; ++j) s[j] = __builtin_amdgcn_readfirstlane(csr[off + e + j]);
    unsigned u[4];
#pragma unroll
    for (int j = 0; j < 4; ++j) u[j] = H1n[(size_t)s[j] * 64 + lane];
#pragma unroll
    for (int j = 0; j < 4; ++j) {
      float2 h = bf2unpack(u[j]);
      acc.x += h.x;
      acc.y += h.y;
    }
  }
  for (; e < cnt; ++e) {
    int s0 = __builtin_amdgcn_readfirstlane(csr[off + e]);
    float2 h0 = bf2unpack(H1n[(size_t)s0 * 64 + lane]);
    acc.x += h0.x;
    acc.y += h0.y;
  }

  float2 bb = *(const float2*)(b1 + c0);
  float v0 = fmaf(acc.x, di, bb.x); v0 = v0 > 0.f ? v0 : 0.f;
  float v1 = fmaf(acc.y, di, bb.y); v1 = v1 > 0.f ? v1 : 0.f;

  float4 wv = *(const float4*)(Wf + c0 * 2);
  float z0 = v0 * wv.x + v1 * wv.z;
  float z1 = v0 * wv.y + v1 * wv.w;
#pragma unroll
  for (int m = 32; m > 0; m >>= 1) {
    z0 += __shfl_xor(z0, m, 64);
    z1 += __shfl_xor(z1, m, 64);
  }
  if (lane == 0) {
    Zn[(size_t)node * 2 + 0] = z0 * di;
    Zn[(size_t)node * 2 + 1] = z1 * di;
  }
}

// ---------- agg2 (thread per node): out = di*(Zn[i] + sum Zn[s]) + bf ----------
__global__ void agg2_kernel(const float* __restrict__ Znb, const int* __restrict__ csr,
                            const int* __restrict__ offsets, const int* __restrict__ counts,
                            const float* __restrict__ dinv, const float* __restrict__ bf,
                            float* __restrict__ out, int n) {
  int i = blockIdx.x * blockDim.x + threadIdx.x;
  if (i >= n) return;
  float di = dinv[i];
  float2 z = *(const float2*)(Znb + (size_t)i * 2);
  float ax = z.x, ay = z.y;   // self-loop term
  int off = offsets[i], cnt = counts[i];
  int e = 0;
  for (; e + 4 <= cnt; e += 4) {
    int s0 = csr[off + e + 0], s1 = csr[off + e + 1];
    int s2 = csr[off + e + 2], s3 = csr[off + e + 3];
    float2 z0 = *(const float2*)(Znb + (size_t)s0 * 2);
    float2 z1 = *(const float2*)(Znb + (size_t)s1 * 2);
    float2 z2 = *(const float2*)(Znb + (size_t)s2 * 2);
    float2 z3 = *(const float2*)(Znb + (size_t)s3 * 2);
    ax += (z0.x + z1.x) + (z2.x + z3.x);
    ay += (z0.y + z1.y) + (z2.y + z3.y);
  }
  for (; e < cnt; ++e) {
    int s = csr[off + e];
    float2 zs = *(const float2*)(Znb + (size_t)s * 2);
    ax += zs.x;
    ay += zs.y;
  }
  out[(size_t)i * 2 + 0] = fmaf(ax, di, bf[0]);
  out[(size_t)i * 2 + 1] = fmaf(ay, di, bf[1]);
}

extern "C" void kernel_launch(void* const* d_in, const int* in_sizes, int n_in,
                              void* d_out, int out_size, void* d_ws, size_t ws_size,
                              hipStream_t stream) {
  const float* x = (const float*)d_in[0];
  const int* ei = (const int*)d_in[1];
  const float* fmask = (const float*)d_in[2];
  const float* W1 = (const float*)d_in[3];
  const float* b1 = (const float*)d_in[4];
  const float* W2 = (const float*)d_in[5];
  const float* b2 = (const float*)d_in[6];
  const float* Wc = (const float*)d_in[7];
  const float* bc = (const float*)d_in[8];

  int N = in_sizes[0] / 128;
  int E = in_sizes[1] / 2;
  const int* src = ei;
  const int* dst = ei + E;

  char* base = (char*)d_ws;
  size_t o = 0;
  auto take = [&](size_t bytes) -> char* {
    char* p = base + o;
    o = (o + bytes + 255) & ~(size_t)255;
    return p;
  };
  int* counts = (int*)take((size_t)N * 4);
  int* offsets = (int*)take((size_t)N * 4);
  float* dinv = (float*)take((size_t)N * 4);
  int* csr = (int*)take((size_t)E * 4);
  unsigned* H1n = (unsigned*)take((size_t)N * 64 * 4);  // packed bf16 rows
  float* Zn = (float*)take((size_t)N * 2 * 4);
  float* sm = (float*)take(128 * 4);
  float* Wf = (float*)take(256 * 4);
  float* bf = (float*)take(2 * 4);
  unsigned* W1Tg = (unsigned*)take(8192 * 4);           // W1^T bf16 packed
  int* hist = (int*)take((size_t)NBIN * PNB * 4);       // partition histogram
  int* binstart = (int*)take((NBIN + 1) * 4);
  unsigned* psd = (unsigned*)take((size_t)E * 4);       // packed (src|ld<<20)
  (void)ws_size;
  (void)n_in;
  (void)out_size;

  // bin(d) = umulhi(d*NBIN, multN) ~ floor(d*NBIN/N); multN = ceil(2^32/N)
  unsigned multN = (unsigned)(((1ull << 32) + N - 1) / (unsigned long long)N);

  histP_prep_kernel<<<PNB + 33, 256, 0, stream>>>(dst, hist, E, multN, fmask, W2, b2,
                                                  Wc, bc, W1, sm, Wf, bf, W1Tg);
  scanP_kernel<<<1, 256, 0, stream>>>(hist, binstart, E);
  partP_kernel<<<PNB, 256, 0, stream>>>(src, dst, hist, psd, E, multN);
  csrbuild_kernel<<<NBIN, 256, 0, stream>>>(psd, binstart, offsets, counts, dinv, csr,
                                            N, multN);
  gemm1_mfma_kernel<<<(N + 127) / 128, 256, 0, stream>>>(x, W1Tg, sm, dinv, H1n, N);
  agg1_kernel<<<(N + 3) / 4, 256, 0, stream>>>(H1n, csr, offsets, counts, dinv, b1, Wf, Zn, N);
  agg2_kernel<<<(N + 255) / 256, 256, 0, stream>>>(Zn, csr, offsets, counts, dinv, bf,
                                                   (float*)d_out, N);
}